// Round 1
// baseline (265.352 us; speedup 1.0000x reference)
//
#include <hip/hip_runtime.h>
#include <hip/hip_bf16.h>
#include <stdint.h>

#define NT 20000
#define DIM 1024
#define HID 512
#define DATT_N 256
#define NCLUS 10
#define NCLS_N 4

typedef __bf16 bf16;
typedef __attribute__((ext_vector_type(8))) __bf16 bf16x8;
typedef __attribute__((ext_vector_type(4))) float f32x4;

__device__ __forceinline__ void gload_lds16(const void* g, void* l) {
  __builtin_amdgcn_global_load_lds(
      (const __attribute__((address_space(1))) unsigned int*)g,
      (__attribute__((address_space(3))) unsigned int*)l, 16, 0, 0);
}

// ---------------- sorting / setup ----------------

__global__ void zero_kernel(int* cnt, float* pool) {
  int i = blockIdx.x * 256 + threadIdx.x;
  if (i < 16) cnt[i] = 0;
  if (i < NCLUS * HID) pool[i] = 0.f;
}

__global__ void count_kernel(const int* __restrict__ cid, int* cnt, int* pos) {
  int n = blockIdx.x * 256 + threadIdx.x;
  if (n < NT) pos[n] = atomicAdd(&cnt[cid[n]], 1);
}

__global__ void offs_kernel(const int* cnt, int* offs) {
  if (threadIdx.x == 0) {
    int a = 0;
    for (int c = 0; c < NCLUS; ++c) { offs[c] = a; a += cnt[c]; }
    offs[NCLUS] = a;
  }
}

__global__ void scatter_kernel(const int* __restrict__ cid, const int* __restrict__ pos,
                               const int* __restrict__ offs, int* order) {
  int n = blockIdx.x * 256 + threadIdx.x;
  if (n < NT) order[offs[cid[n]] + pos[n]] = n;
}

// dst[b][j][i] = bf16(src[b][i][j]) ; src is R x Cc per batch b
__global__ void transpose_cast(const float* __restrict__ src, bf16* __restrict__ dst,
                               int R, int Cc) {
  __shared__ float t[32][33];
  int b = blockIdx.z;
  int i0 = blockIdx.y * 32, j0 = blockIdx.x * 32;
  const float* s = src + (size_t)b * R * Cc;
  bf16* d = dst + (size_t)b * R * Cc;
  int tx = threadIdx.x & 31, ty = threadIdx.x >> 5;
#pragma unroll
  for (int yy = 0; yy < 32; yy += 8)
    t[ty + yy][tx] = s[(size_t)(i0 + ty + yy) * Cc + (j0 + tx)];
  __syncthreads();
#pragma unroll
  for (int yy = 0; yy < 32; yy += 8)
    d[(size_t)(j0 + ty + yy) * R + (i0 + tx)] = (bf16)t[tx][ty + yy];
}

// ---------------- GEMM1: h1 = relu(x_gathered @ W1[c] + b1[c]) ----------------

__global__ __launch_bounds__(256, 2) void gemm1_kernel(
    const float* __restrict__ x, const bf16* __restrict__ w1t, const float* __restrict__ b1,
    const int* __restrict__ order, const int* __restrict__ offs, const int* __restrict__ cnt,
    bf16* __restrict__ h1) {
  int c = blockIdx.z;
  int cntc = cnt[c];
  int row0 = blockIdx.y * 128;
  if (row0 >= cntc) return;
  int seg = offs[c];
  int n0 = blockIdx.x * 128;

  __shared__ bf16 Als[128 * 64];  // [row][k]
  __shared__ bf16 Bls[128 * 64];  // [n][k]  (B^T)

  int tid = threadIdx.x;
  int lane = tid & 63, wid = tid >> 6;
  int wr = wid >> 1, wc = wid & 1;

  // A staging (reg-staged: gather fp32 rows, cast to bf16)
  const float* aptr[4];
  int aoff[4];
#pragma unroll
  for (int i = 0; i < 4; ++i) {
    int chunk = i * 256 + tid;       // 0..1023 -> 8 elems each
    int r = chunk >> 3;              // 0..127
    int k8 = (chunk & 7) << 3;       // 0..56
    int rr = row0 + r; if (rr > cntc - 1) rr = cntc - 1;
    int gr = order[seg + rr];
    aptr[i] = x + (size_t)gr * DIM + k8;
    aoff[i] = r * 64 + k8;
  }
  // B staging (global_load_lds, wave-uniform LDS base + lane*16)
  const bf16* bptr[4];
  int boff[4];
#pragma unroll
  for (int i = 0; i < 4; ++i) {
    int chunk = i * 4 + wid;               // 0..15, 512 elems each
    int r = chunk * 8 + (lane >> 3);       // B row (n) 0..127
    int kk = (lane & 7) << 3;
    bptr[i] = w1t + (size_t)(c * HID + n0 + r) * DIM + kk;
    boff[i] = chunk * 512;
  }

  f32x4 acc[4][4];
#pragma unroll
  for (int m = 0; m < 4; m++)
#pragma unroll
    for (int n = 0; n < 4; n++) acc[m][n] = {0.f, 0.f, 0.f, 0.f};

  for (int k0 = 0; k0 < DIM; k0 += 64) {
#pragma unroll
    for (int i = 0; i < 4; ++i) gload_lds16(bptr[i] + k0, &Bls[boff[i]]);
#pragma unroll
    for (int i = 0; i < 4; ++i) {
      const f32x4* sp = (const f32x4*)(aptr[i] + k0);
      f32x4 u = sp[0], v = sp[1];
      bf16x8 w;
      w[0] = (bf16)u[0]; w[1] = (bf16)u[1]; w[2] = (bf16)u[2]; w[3] = (bf16)u[3];
      w[4] = (bf16)v[0]; w[5] = (bf16)v[1]; w[6] = (bf16)v[2]; w[7] = (bf16)v[3];
      *(bf16x8*)(&Als[aoff[i]]) = w;
    }
    __syncthreads();
#pragma unroll
    for (int ks = 0; ks < 2; ++ks) {
      int ko = ks * 32 + ((lane >> 4) << 3);
      bf16x8 a[4], b[4];
#pragma unroll
      for (int m = 0; m < 4; m++)
        a[m] = *(const bf16x8*)(&Als[(wr * 64 + m * 16 + (lane & 15)) * 64 + ko]);
#pragma unroll
      for (int n = 0; n < 4; n++)
        b[n] = *(const bf16x8*)(&Bls[(wc * 64 + n * 16 + (lane & 15)) * 64 + ko]);
#pragma unroll
      for (int m = 0; m < 4; m++)
#pragma unroll
        for (int n = 0; n < 4; n++)
          acc[m][n] = __builtin_amdgcn_mfma_f32_16x16x32_bf16(a[m], b[n], acc[m][n], 0, 0, 0);
    }
    __syncthreads();
  }

  int valid = cntc - row0; if (valid > 128) valid = 128;
#pragma unroll
  for (int n = 0; n < 4; n++) {
    int col = n0 + wc * 64 + n * 16 + (lane & 15);
    float bias = b1[c * HID + col];
#pragma unroll
    for (int m = 0; m < 4; m++) {
      int rbase = wr * 64 + m * 16 + ((lane >> 4) << 2);
#pragma unroll
      for (int e = 0; e < 4; e++) {
        int r = rbase + e;
        if (r < valid) {
          float v = acc[m][n][e] + bias;
          h1[(size_t)(seg + row0 + r) * HID + col] = (bf16)(v > 0.f ? v : 0.f);
        }
      }
    }
  }
}

// ---------------- GEMM2: pool[c] += colsum(relu(h1 @ W2[c] + b2[c])) ----------------

__global__ __launch_bounds__(256, 2) void gemm2_kernel(
    const bf16* __restrict__ h1, const bf16* __restrict__ w2t, const float* __restrict__ b2,
    const int* __restrict__ offs, const int* __restrict__ cnt, float* __restrict__ pool) {
  int c = blockIdx.z;
  int cntc = cnt[c];
  int row0 = blockIdx.y * 128;
  if (row0 >= cntc) return;
  int seg = offs[c];
  int n0 = blockIdx.x * 128;
  int valid = cntc - row0; if (valid > 128) valid = 128;

  __shared__ bf16 Als[128 * 64];
  __shared__ bf16 Bls[128 * 64];

  int tid = threadIdx.x;
  int lane = tid & 63, wid = tid >> 6;
  int wr = wid >> 1, wc = wid & 1;

  const bf16* aptr[4]; int aoff[4];
  const bf16* bptr[4]; int boff[4];
#pragma unroll
  for (int i = 0; i < 4; ++i) {
    int chunk = i * 4 + wid;
    int r = chunk * 8 + (lane >> 3);
    int kk = (lane & 7) << 3;
    int rr = r; if (rr > valid - 1) rr = valid - 1;
    aptr[i] = h1 + (size_t)(seg + row0 + rr) * HID + kk;
    aoff[i] = chunk * 512;
    bptr[i] = w2t + (size_t)(c * HID + n0 + r) * HID + kk;
    boff[i] = chunk * 512;
  }

  f32x4 acc[4][4];
#pragma unroll
  for (int m = 0; m < 4; m++)
#pragma unroll
    for (int n = 0; n < 4; n++) acc[m][n] = {0.f, 0.f, 0.f, 0.f};

  for (int k0 = 0; k0 < HID; k0 += 64) {
#pragma unroll
    for (int i = 0; i < 4; ++i) gload_lds16(aptr[i] + k0, &Als[aoff[i]]);
#pragma unroll
    for (int i = 0; i < 4; ++i) gload_lds16(bptr[i] + k0, &Bls[boff[i]]);
    __syncthreads();
#pragma unroll
    for (int ks = 0; ks < 2; ++ks) {
      int ko = ks * 32 + ((lane >> 4) << 3);
      bf16x8 a[4], b[4];
#pragma unroll
      for (int m = 0; m < 4; m++)
        a[m] = *(const bf16x8*)(&Als[(wr * 64 + m * 16 + (lane & 15)) * 64 + ko]);
#pragma unroll
      for (int n = 0; n < 4; n++)
        b[n] = *(const bf16x8*)(&Bls[(wc * 64 + n * 16 + (lane & 15)) * 64 + ko]);
#pragma unroll
      for (int m = 0; m < 4; m++)
#pragma unroll
        for (int n = 0; n < 4; n++)
          acc[m][n] = __builtin_amdgcn_mfma_f32_16x16x32_bf16(a[m], b[n], acc[m][n], 0, 0, 0);
    }
    __syncthreads();
  }

  // bias + relu + masked column-sum into pool
#pragma unroll
  for (int n = 0; n < 4; n++) {
    int col = n0 + wc * 64 + n * 16 + (lane & 15);
    float bias = b2[c * HID + col];
    float s = 0.f;
#pragma unroll
    for (int m = 0; m < 4; m++) {
      int rbase = wr * 64 + m * 16 + ((lane >> 4) << 2);
#pragma unroll
      for (int e = 0; e < 4; e++) {
        if (rbase + e < valid) {
          float v = acc[m][n][e] + bias;
          s += (v > 0.f ? v : 0.f);
        }
      }
    }
    s += __shfl_xor(s, 16);
    s += __shfl_xor(s, 32);
    if (lane < 16) atomicAdd(&pool[c * HID + n0 + wc * 64 + n * 16 + lane], s);
  }
}

// ---------------- tails (fp32) ----------------

__global__ void tail_a(const float* __restrict__ pool, const int* __restrict__ cnt,
                       const float* __restrict__ fcW, const float* __restrict__ fcb,
                       const float* __restrict__ Wa, const float* __restrict__ ba,
                       const float* __restrict__ Wb, const float* __restrict__ bb,
                       const float* __restrict__ Wc, const float* __restrict__ bc,
                       float* __restrict__ hbuf, float* __restrict__ score) {
  int c = blockIdx.x;
  __shared__ float hc[HID];
  __shared__ float h[HID];
  __shared__ float red[256];
  int tid = threadIdx.x;
  float inv = 1.f / fmaxf((float)cnt[c], 1.f);
  for (int k = tid; k < HID; k += 256) hc[k] = pool[c * HID + k] * inv;
  __syncthreads();
  for (int j = tid; j < HID; j += 256) {
    float s = fcb[j];
    for (int k = 0; k < HID; k++) s += hc[k] * fcW[(size_t)k * HID + j];
    s = fmaxf(s, 0.f);
    h[j] = s;
    hbuf[c * HID + j] = s;
  }
  __syncthreads();
  float part = 0.f;
  for (int j = tid; j < DATT_N; j += 256) {
    float sa = ba[j], sb = bb[j];
    for (int k = 0; k < HID; k++) {
      float hv = h[k];
      sa += hv * Wa[(size_t)k * DATT_N + j];
      sb += hv * Wb[(size_t)k * DATT_N + j];
    }
    float av = tanhf(sa);
    float bv = 1.f / (1.f + expf(-sb));
    part += av * bv * Wc[j];
  }
  red[tid] = part;
  __syncthreads();
  for (int s2 = 128; s2 > 0; s2 >>= 1) {
    if (tid < s2) red[tid] += red[tid + s2];
    __syncthreads();
  }
  if (tid == 0) score[c] = red[0] + bc[0];
}

__global__ void tail_b(const float* __restrict__ score, const float* __restrict__ hbuf,
                       const float* __restrict__ rhoW, const float* __restrict__ rhob,
                       const float* __restrict__ clsW, const float* __restrict__ clsb,
                       float* __restrict__ out) {
  __shared__ float Asm[NCLUS];
  __shared__ float hp[HID];
  __shared__ float hr[DATT_N];
  __shared__ float lg[NCLS_N];
  int tid = threadIdx.x;
  if (tid == 0) {
    float mx = -1e30f;
    for (int c = 0; c < NCLUS; c++) mx = fmaxf(mx, score[c]);
    float sum = 0.f, e[NCLUS];
    for (int c = 0; c < NCLUS; c++) { e[c] = expf(score[c] - mx); sum += e[c]; }
    for (int c = 0; c < NCLUS; c++) Asm[c] = e[c] / sum;
  }
  __syncthreads();
  for (int k = tid; k < HID; k += 256) {
    float s = 0.f;
    for (int c = 0; c < NCLUS; c++) s += Asm[c] * hbuf[c * HID + k];
    hp[k] = s;
  }
  __syncthreads();
  for (int j = tid; j < DATT_N; j += 256) {
    float s = rhob[j];
    for (int k = 0; k < HID; k++) s += hp[k] * rhoW[(size_t)k * DATT_N + j];
    hr[j] = fmaxf(s, 0.f);
  }
  __syncthreads();
  if (tid < NCLS_N) {
    float s = clsb[tid];
    for (int j = 0; j < DATT_N; j++) s += hr[j] * clsW[j * NCLS_N + tid];
    lg[tid] = s;
  }
  __syncthreads();
  if (tid == 0) {
    float mx = lg[0];
    int am = 0;
    for (int t = 1; t < NCLS_N; t++) if (lg[t] > mx) { mx = lg[t]; am = t; }
    float sum = 0.f, e[NCLS_N];
    for (int t = 0; t < NCLS_N; t++) { e[t] = expf(lg[t] - mx); sum += e[t]; }
    for (int t = 0; t < NCLS_N; t++) {
      out[t] = lg[t];
      out[NCLS_N + t] = e[t] / sum;
    }
    out[2 * NCLS_N] = (float)am;
  }
}

// ---------------- launch ----------------

extern "C" void kernel_launch(void* const* d_in, const int* in_sizes, int n_in,
                              void* d_out, int out_size, void* d_ws, size_t ws_size,
                              hipStream_t stream) {
  const float* x    = (const float*)d_in[0];
  const int*   cid  = (const int*)d_in[1];
  const float* W1   = (const float*)d_in[2];
  const float* b1   = (const float*)d_in[3];
  const float* W2   = (const float*)d_in[4];
  const float* b2   = (const float*)d_in[5];
  const float* fcW  = (const float*)d_in[6];
  const float* fcb  = (const float*)d_in[7];
  const float* Wa   = (const float*)d_in[8];
  const float* ba   = (const float*)d_in[9];
  const float* Wb   = (const float*)d_in[10];
  const float* bb   = (const float*)d_in[11];
  const float* Wc   = (const float*)d_in[12];
  const float* bc   = (const float*)d_in[13];
  const float* rhoW = (const float*)d_in[14];
  const float* rhob = (const float*)d_in[15];
  const float* clsW = (const float*)d_in[16];
  const float* clsb = (const float*)d_in[17];
  float* out = (float*)d_out;

  char* ws = (char*)d_ws;
  int*   cnt   = (int*)(ws + 0);
  int*   offs  = (int*)(ws + 64);
  float* score = (float*)(ws + 128);
  int*   pos   = (int*)(ws + 256);
  int*   order = (int*)(ws + 256 + 80000);
  float* pool  = (float*)(ws + 256 + 160000);
  float* hbuf  = (float*)(ws + 256 + 160000 + NCLUS * HID * 4);
  size_t o = 256 + 160000 + 2ull * NCLUS * HID * 4;
  o = (o + 255) & ~(size_t)255;
  bf16* w1t = (bf16*)(ws + o); o += (size_t)NCLUS * HID * DIM * 2;
  bf16* w2t = (bf16*)(ws + o); o += (size_t)NCLUS * HID * HID * 2;
  bf16* h1  = (bf16*)(ws + o); o += (size_t)NT * HID * 2;

  zero_kernel<<<dim3((NCLUS * HID + 255) / 256), dim3(256), 0, stream>>>(cnt, pool);
  count_kernel<<<dim3((NT + 255) / 256), dim3(256), 0, stream>>>(cid, cnt, pos);
  offs_kernel<<<dim3(1), dim3(64), 0, stream>>>(cnt, offs);
  scatter_kernel<<<dim3((NT + 255) / 256), dim3(256), 0, stream>>>(cid, pos, offs, order);
  transpose_cast<<<dim3(HID / 32, DIM / 32, NCLUS), dim3(256), 0, stream>>>(W1, w1t, DIM, HID);
  transpose_cast<<<dim3(HID / 32, HID / 32, NCLUS), dim3(256), 0, stream>>>(W2, w2t, HID, HID);
  gemm1_kernel<<<dim3(4, (NT + 127) / 128, NCLUS), dim3(256), 0, stream>>>(
      x, w1t, b1, order, offs, cnt, h1);
  gemm2_kernel<<<dim3(4, (NT + 127) / 128, NCLUS), dim3(256), 0, stream>>>(
      h1, w2t, b2, offs, cnt, pool);
  tail_a<<<dim3(NCLUS), dim3(256), 0, stream>>>(pool, cnt, fcW, fcb, Wa, ba, Wb, bb, Wc, bc,
                                                hbuf, score);
  tail_b<<<dim3(1), dim3(256), 0, stream>>>(score, hbuf, rhoW, rhob, clsW, clsb, out);
}

// Round 2
// 249.851 us; speedup vs baseline: 1.0620x; 1.0620x over previous
//
#include <hip/hip_runtime.h>
#include <hip/hip_bf16.h>
#include <stdint.h>

#define NT 20000
#define DIM 1024
#define HID 512
#define DATT_N 256
#define NCLUS 10
#define NCLS_N 4
#define NRT 157  // ceil(NT/128)

typedef __bf16 bf16;
typedef __attribute__((ext_vector_type(8))) __bf16 bf16x8;
typedef __attribute__((ext_vector_type(4))) float f32x4;

__device__ __forceinline__ void gload_lds16(const void* g, void* l) {
  __builtin_amdgcn_global_load_lds(
      (const __attribute__((address_space(1))) unsigned int*)g,
      (__attribute__((address_space(3))) unsigned int*)l, 16, 0, 0);
}

// ---------------- sorting / setup ----------------

__global__ void zero_kernel(int* cnt, float* pool) {
  int i = blockIdx.x * 256 + threadIdx.x;
  if (i < 16) cnt[i] = 0;
  if (i < NCLUS * HID) pool[i] = 0.f;
}

__global__ void count_kernel(const int* __restrict__ cid, int* cnt, int* pos) {
  int n = blockIdx.x * 256 + threadIdx.x;
  if (n < NT) pos[n] = atomicAdd(&cnt[cid[n]], 1);
}

__global__ void offs_kernel(const int* cnt, int* offs) {
  if (threadIdx.x == 0) {
    int a = 0;
    for (int c = 0; c < NCLUS; ++c) { offs[c] = a; a += cnt[c]; }
    offs[NCLUS] = a;
  }
}

__global__ void scatter_kernel(const int* __restrict__ cid, const int* __restrict__ pos,
                               const int* __restrict__ offs, int* order) {
  int n = blockIdx.x * 256 + threadIdx.x;
  if (n < NT) order[offs[cid[n]] + pos[n]] = n;
}

// xs[i][:] = bf16(x[order[i]][:])  -- sorted, casted copy of x
__global__ void gather_cast(const float* __restrict__ x, const int* __restrict__ order,
                            bf16* __restrict__ xs) {
  int t = blockIdx.x * 256 + threadIdx.x;  // one thread per 8 elements
  int row = t >> 7;                        // 128 threads per row (1024 elems)
  if (row >= NT) return;
  int col = (t & 127) << 3;
  const f32x4* p = (const f32x4*)(x + (size_t)order[row] * DIM + col);
  f32x4 u = p[0], v = p[1];
  bf16x8 w;
  w[0] = (bf16)u[0]; w[1] = (bf16)u[1]; w[2] = (bf16)u[2]; w[3] = (bf16)u[3];
  w[4] = (bf16)v[0]; w[5] = (bf16)v[1]; w[6] = (bf16)v[2]; w[7] = (bf16)v[3];
  *(bf16x8*)(xs + (size_t)row * DIM + col) = w;
}

// dst[b][j][i] = bf16(src[b][i][j]) ; src is R x Cc per batch b
__global__ void transpose_cast(const float* __restrict__ src, bf16* __restrict__ dst,
                               int R, int Cc) {
  __shared__ float t[32][33];
  int b = blockIdx.z;
  int i0 = blockIdx.y * 32, j0 = blockIdx.x * 32;
  const float* s = src + (size_t)b * R * Cc;
  bf16* d = dst + (size_t)b * R * Cc;
  int tx = threadIdx.x & 31, ty = threadIdx.x >> 5;
#pragma unroll
  for (int yy = 0; yy < 32; yy += 8)
    t[ty + yy][tx] = s[(size_t)(i0 + ty + yy) * Cc + (j0 + tx)];
  __syncthreads();
#pragma unroll
  for (int yy = 0; yy < 32; yy += 8)
    d[(size_t)(j0 + ty + yy) * R + (i0 + tx)] = (bf16)t[tx][ty + yy];
}

// XCD-grouping decode: the 4 n-blocks of one (cluster,row-tile) group get
// dispatch slots congruent mod 8 -> same XCD L2 serves the shared A panel.
__device__ __forceinline__ bool decode_grp(int d, int& c, int& rt, int& j) {
  int x8 = d & 7, s = d >> 3;
  int g = (s >> 2) * 8 + x8;
  if (g >= NRT * NCLUS) return false;
  j = s & 3;
  c = g / NRT;
  rt = g - c * NRT;
  return true;
}

// ---------------- GEMM1: h1 = relu(xs @ W1[c]^T + b1[c]) ----------------

__global__ __launch_bounds__(256, 2) void gemm1_kernel(
    const bf16* __restrict__ xs, const bf16* __restrict__ w1t, const float* __restrict__ b1,
    const int* __restrict__ offs, const int* __restrict__ cnt, bf16* __restrict__ h1) {
  int c, rt, j;
  if (!decode_grp(blockIdx.x, c, rt, j)) return;
  int cntc = cnt[c];
  int row0 = rt * 128;
  if (row0 >= cntc) return;
  int seg = offs[c];
  int n0 = j * 128;

  __shared__ bf16 Als[128 * 64];  // [row][k]
  __shared__ bf16 Bls[128 * 64];  // [n][k]

  int tid = threadIdx.x;
  int lane = tid & 63, wid = tid >> 6;
  int wr = wid >> 1, wc = wid & 1;

  const bf16* aptr[4]; int aoff[4];
  const bf16* bptr[4]; int boff[4];
#pragma unroll
  for (int i = 0; i < 4; ++i) {
    int chunk = i * 4 + wid;              // 0..15, 512 bf16 per wave-chunk
    int r = chunk * 8 + (lane >> 3);      // tile row 0..127
    int kk = (lane & 7) << 3;
    int ar = seg + row0 + r; if (ar > NT - 1) ar = NT - 1;
    aptr[i] = xs + (size_t)ar * DIM + kk;
    aoff[i] = chunk * 512;
    bptr[i] = w1t + (size_t)(c * HID + n0 + r) * DIM + kk;
    boff[i] = chunk * 512;
  }

  f32x4 acc[4][4];
#pragma unroll
  for (int m = 0; m < 4; m++)
#pragma unroll
    for (int n = 0; n < 4; n++) acc[m][n] = {0.f, 0.f, 0.f, 0.f};

  for (int k0 = 0; k0 < DIM; k0 += 64) {
#pragma unroll
    for (int i = 0; i < 4; ++i) gload_lds16(aptr[i] + k0, &Als[aoff[i]]);
#pragma unroll
    for (int i = 0; i < 4; ++i) gload_lds16(bptr[i] + k0, &Bls[boff[i]]);
    __syncthreads();
#pragma unroll
    for (int ks = 0; ks < 2; ++ks) {
      int ko = ks * 32 + ((lane >> 4) << 3);
      bf16x8 a[4], b[4];
#pragma unroll
      for (int m = 0; m < 4; m++)
        a[m] = *(const bf16x8*)(&Als[(wr * 64 + m * 16 + (lane & 15)) * 64 + ko]);
#pragma unroll
      for (int n = 0; n < 4; n++)
        b[n] = *(const bf16x8*)(&Bls[(wc * 64 + n * 16 + (lane & 15)) * 64 + ko]);
#pragma unroll
      for (int m = 0; m < 4; m++)
#pragma unroll
        for (int n = 0; n < 4; n++)
          acc[m][n] = __builtin_amdgcn_mfma_f32_16x16x32_bf16(a[m], b[n], acc[m][n], 0, 0, 0);
    }
    __syncthreads();
  }

  int valid = cntc - row0; if (valid > 128) valid = 128;
#pragma unroll
  for (int n = 0; n < 4; n++) {
    int col = n0 + wc * 64 + n * 16 + (lane & 15);
    float bias = b1[c * HID + col];
#pragma unroll
    for (int m = 0; m < 4; m++) {
      int rbase = wr * 64 + m * 16 + ((lane >> 4) << 2);
#pragma unroll
      for (int e = 0; e < 4; e++) {
        int r = rbase + e;
        if (r < valid) {
          float v = acc[m][n][e] + bias;
          h1[(size_t)(seg + row0 + r) * HID + col] = (bf16)(v > 0.f ? v : 0.f);
        }
      }
    }
  }
}

// ---------------- GEMM2: pool[c] += colsum(relu(h1 @ W2[c]^T + b2[c])) ----------------

__global__ __launch_bounds__(256, 2) void gemm2_kernel(
    const bf16* __restrict__ h1, const bf16* __restrict__ w2t, const float* __restrict__ b2,
    const int* __restrict__ offs, const int* __restrict__ cnt, float* __restrict__ pool) {
  int c, rt, j;
  if (!decode_grp(blockIdx.x, c, rt, j)) return;
  int cntc = cnt[c];
  int row0 = rt * 128;
  if (row0 >= cntc) return;
  int seg = offs[c];
  int n0 = j * 128;
  int valid = cntc - row0; if (valid > 128) valid = 128;

  __shared__ bf16 Als[128 * 64];
  __shared__ bf16 Bls[128 * 64];

  int tid = threadIdx.x;
  int lane = tid & 63, wid = tid >> 6;
  int wr = wid >> 1, wc = wid & 1;

  const bf16* aptr[4]; int aoff[4];
  const bf16* bptr[4]; int boff[4];
#pragma unroll
  for (int i = 0; i < 4; ++i) {
    int chunk = i * 4 + wid;
    int r = chunk * 8 + (lane >> 3);
    int kk = (lane & 7) << 3;
    int ar = seg + row0 + r; if (ar > NT - 1) ar = NT - 1;
    aptr[i] = h1 + (size_t)ar * HID + kk;
    aoff[i] = chunk * 512;
    bptr[i] = w2t + (size_t)(c * HID + n0 + r) * HID + kk;
    boff[i] = chunk * 512;
  }

  f32x4 acc[4][4];
#pragma unroll
  for (int m = 0; m < 4; m++)
#pragma unroll
    for (int n = 0; n < 4; n++) acc[m][n] = {0.f, 0.f, 0.f, 0.f};

  for (int k0 = 0; k0 < HID; k0 += 64) {
#pragma unroll
    for (int i = 0; i < 4; ++i) gload_lds16(aptr[i] + k0, &Als[aoff[i]]);
#pragma unroll
    for (int i = 0; i < 4; ++i) gload_lds16(bptr[i] + k0, &Bls[boff[i]]);
    __syncthreads();
#pragma unroll
    for (int ks = 0; ks < 2; ++ks) {
      int ko = ks * 32 + ((lane >> 4) << 3);
      bf16x8 a[4], b[4];
#pragma unroll
      for (int m = 0; m < 4; m++)
        a[m] = *(const bf16x8*)(&Als[(wr * 64 + m * 16 + (lane & 15)) * 64 + ko]);
#pragma unroll
      for (int n = 0; n < 4; n++)
        b[n] = *(const bf16x8*)(&Bls[(wc * 64 + n * 16 + (lane & 15)) * 64 + ko]);
#pragma unroll
      for (int m = 0; m < 4; m++)
#pragma unroll
        for (int n = 0; n < 4; n++)
          acc[m][n] = __builtin_amdgcn_mfma_f32_16x16x32_bf16(a[m], b[n], acc[m][n], 0, 0, 0);
    }
    __syncthreads();
  }

  // bias + relu + masked column-sum into pool
#pragma unroll
  for (int n = 0; n < 4; n++) {
    int col = n0 + wc * 64 + n * 16 + (lane & 15);
    float bias = b2[c * HID + col];
    float s = 0.f;
#pragma unroll
    for (int m = 0; m < 4; m++) {
      int rbase = wr * 64 + m * 16 + ((lane >> 4) << 2);
#pragma unroll
      for (int e = 0; e < 4; e++) {
        if (rbase + e < valid) {
          float v = acc[m][n][e] + bias;
          s += (v > 0.f ? v : 0.f);
        }
      }
    }
    s += __shfl_xor(s, 16);
    s += __shfl_xor(s, 32);
    if (lane < 16) atomicAdd(&pool[c * HID + n0 + wc * 64 + n * 16 + lane], s);
  }
}

// ---------------- tails (fp32) ----------------

__global__ void tail_a(const float* __restrict__ pool, const int* __restrict__ cnt,
                       const float* __restrict__ fcW, const float* __restrict__ fcb,
                       const float* __restrict__ Wa, const float* __restrict__ ba,
                       const float* __restrict__ Wb, const float* __restrict__ bb,
                       const float* __restrict__ Wc, const float* __restrict__ bc,
                       float* __restrict__ hbuf, float* __restrict__ score) {
  int c = blockIdx.x;
  __shared__ float hc[HID];
  __shared__ float h[HID];
  __shared__ float red[256];
  int tid = threadIdx.x;
  float inv = 1.f / fmaxf((float)cnt[c], 1.f);
  for (int k = tid; k < HID; k += 256) hc[k] = pool[c * HID + k] * inv;
  __syncthreads();
  for (int j = tid; j < HID; j += 256) {
    float s = fcb[j];
    for (int k = 0; k < HID; k++) s += hc[k] * fcW[(size_t)k * HID + j];
    s = fmaxf(s, 0.f);
    h[j] = s;
    hbuf[c * HID + j] = s;
  }
  __syncthreads();
  float part = 0.f;
  for (int j = tid; j < DATT_N; j += 256) {
    float sa = ba[j], sb = bb[j];
    for (int k = 0; k < HID; k++) {
      float hv = h[k];
      sa += hv * Wa[(size_t)k * DATT_N + j];
      sb += hv * Wb[(size_t)k * DATT_N + j];
    }
    float av = tanhf(sa);
    float bv = 1.f / (1.f + expf(-sb));
    part += av * bv * Wc[j];
  }
  red[tid] = part;
  __syncthreads();
  for (int s2 = 128; s2 > 0; s2 >>= 1) {
    if (tid < s2) red[tid] += red[tid + s2];
    __syncthreads();
  }
  if (tid == 0) score[c] = red[0] + bc[0];
}

__global__ void tail_b(const float* __restrict__ score, const float* __restrict__ hbuf,
                       const float* __restrict__ rhoW, const float* __restrict__ rhob,
                       const float* __restrict__ clsW, const float* __restrict__ clsb,
                       float* __restrict__ out) {
  __shared__ float Asm[NCLUS];
  __shared__ float hp[HID];
  __shared__ float hr[DATT_N];
  __shared__ float lg[NCLS_N];
  int tid = threadIdx.x;
  if (tid == 0) {
    float mx = -1e30f;
    for (int c = 0; c < NCLUS; c++) mx = fmaxf(mx, score[c]);
    float sum = 0.f, e[NCLUS];
    for (int c = 0; c < NCLUS; c++) { e[c] = expf(score[c] - mx); sum += e[c]; }
    for (int c = 0; c < NCLUS; c++) Asm[c] = e[c] / sum;
  }
  __syncthreads();
  for (int k = tid; k < HID; k += 256) {
    float s = 0.f;
    for (int c = 0; c < NCLUS; c++) s += Asm[c] * hbuf[c * HID + k];
    hp[k] = s;
  }
  __syncthreads();
  for (int j = tid; j < DATT_N; j += 256) {
    float s = rhob[j];
    for (int k = 0; k < HID; k++) s += hp[k] * rhoW[(size_t)k * DATT_N + j];
    hr[j] = fmaxf(s, 0.f);
  }
  __syncthreads();
  if (tid < NCLS_N) {
    float s = clsb[tid];
    for (int j = 0; j < DATT_N; j++) s += hr[j] * clsW[j * NCLS_N + tid];
    lg[tid] = s;
  }
  __syncthreads();
  if (tid == 0) {
    float mx = lg[0];
    int am = 0;
    for (int t = 1; t < NCLS_N; t++) if (lg[t] > mx) { mx = lg[t]; am = t; }
    float sum = 0.f, e[NCLS_N];
    for (int t = 0; t < NCLS_N; t++) { e[t] = expf(lg[t] - mx); sum += e[t]; }
    for (int t = 0; t < NCLS_N; t++) {
      out[t] = lg[t];
      out[NCLS_N + t] = e[t] / sum;
    }
    out[2 * NCLS_N] = (float)am;
  }
}

// ---------------- launch ----------------

extern "C" void kernel_launch(void* const* d_in, const int* in_sizes, int n_in,
                              void* d_out, int out_size, void* d_ws, size_t ws_size,
                              hipStream_t stream) {
  const float* x    = (const float*)d_in[0];
  const int*   cid  = (const int*)d_in[1];
  const float* W1   = (const float*)d_in[2];
  const float* b1   = (const float*)d_in[3];
  const float* W2   = (const float*)d_in[4];
  const float* b2   = (const float*)d_in[5];
  const float* fcW  = (const float*)d_in[6];
  const float* fcb  = (const float*)d_in[7];
  const float* Wa   = (const float*)d_in[8];
  const float* ba   = (const float*)d_in[9];
  const float* Wb   = (const float*)d_in[10];
  const float* bb   = (const float*)d_in[11];
  const float* Wc   = (const float*)d_in[12];
  const float* bc   = (const float*)d_in[13];
  const float* rhoW = (const float*)d_in[14];
  const float* rhob = (const float*)d_in[15];
  const float* clsW = (const float*)d_in[16];
  const float* clsb = (const float*)d_in[17];
  float* out = (float*)d_out;

  char* ws = (char*)d_ws;
  int*   cnt   = (int*)(ws + 0);
  int*   offs  = (int*)(ws + 64);
  float* score = (float*)(ws + 128);
  int*   pos   = (int*)(ws + 256);
  int*   order = (int*)(ws + 256 + 80000);
  float* pool  = (float*)(ws + 256 + 160000);
  float* hbuf  = (float*)(ws + 256 + 160000 + NCLUS * HID * 4);
  size_t o = 256 + 160000 + 2ull * NCLUS * HID * 4;
  o = (o + 255) & ~(size_t)255;
  bf16* w1t = (bf16*)(ws + o); o += (size_t)NCLUS * HID * DIM * 2;
  bf16* w2t = (bf16*)(ws + o); o += (size_t)NCLUS * HID * HID * 2;
  bf16* h1  = (bf16*)(ws + o); o += (size_t)NT * HID * 2;
  bf16* xs  = (bf16*)(ws + o); o += (size_t)NT * DIM * 2;

  zero_kernel<<<dim3((NCLUS * HID + 255) / 256), dim3(256), 0, stream>>>(cnt, pool);
  count_kernel<<<dim3((NT + 255) / 256), dim3(256), 0, stream>>>(cid, cnt, pos);
  offs_kernel<<<dim3(1), dim3(64), 0, stream>>>(cnt, offs);
  scatter_kernel<<<dim3((NT + 255) / 256), dim3(256), 0, stream>>>(cid, pos, offs, order);
  gather_cast<<<dim3(NT * 128 / 256), dim3(256), 0, stream>>>(x, order, xs);
  transpose_cast<<<dim3(HID / 32, DIM / 32, NCLUS), dim3(256), 0, stream>>>(W1, w1t, DIM, HID);
  transpose_cast<<<dim3(HID / 32, HID / 32, NCLUS), dim3(256), 0, stream>>>(W2, w2t, HID, HID);

  // 8 XCDs x ceil(1570/8)=197 groups x 4 n-blocks
  int nblk = 8 * ((NRT * NCLUS + 7) / 8) * 4;
  gemm1_kernel<<<dim3(nblk), dim3(256), 0, stream>>>(xs, w1t, b1, offs, cnt, h1);
  gemm2_kernel<<<dim3(nblk), dim3(256), 0, stream>>>(h1, w2t, b2, offs, cnt, pool);
  tail_a<<<dim3(NCLUS), dim3(256), 0, stream>>>(pool, cnt, fcW, fcb, Wa, ba, Wb, bb, Wc, bc,
                                                hbuf, score);
  tail_b<<<dim3(1), dim3(256), 0, stream>>>(score, hbuf, rhoW, rhob, clsW, clsb, out);
}

// Round 3
// 211.569 us; speedup vs baseline: 1.2542x; 1.1809x over previous
//
#include <hip/hip_runtime.h>
#include <hip/hip_bf16.h>
#include <stdint.h>

#define NT 20000
#define DIM 1024
#define HID 512
#define DATT_N 256
#define NCLUS 10
#define NCLS_N 4
#define NRT 157  // ceil(NT/128)

typedef __bf16 bf16;
typedef __attribute__((ext_vector_type(8))) __bf16 bf16x8;
typedef __attribute__((ext_vector_type(4))) float f32x4;

__device__ __forceinline__ void gload_lds16(const void* g, void* l) {
  __builtin_amdgcn_global_load_lds(
      (const __attribute__((address_space(1))) unsigned int*)g,
      (__attribute__((address_space(3))) unsigned int*)l, 16, 0, 0);
}

// ---------------- sorting / setup ----------------

__global__ void zero_kernel(int* cnt, float* pool) {
  int i = blockIdx.x * 256 + threadIdx.x;
  if (i < 16) cnt[i] = 0;
  if (i < NCLUS * HID) pool[i] = 0.f;
}

__global__ void count_kernel(const int* __restrict__ cid, int* cnt, int* pos) {
  int n = blockIdx.x * 256 + threadIdx.x;
  if (n < NT) pos[n] = atomicAdd(&cnt[cid[n]], 1);
}

__global__ void offs_kernel(const int* cnt, int* offs) {
  if (threadIdx.x == 0) {
    int a = 0;
    for (int c = 0; c < NCLUS; ++c) { offs[c] = a; a += cnt[c]; }
    offs[NCLUS] = a;
  }
}

__global__ void scatter_kernel(const int* __restrict__ cid, const int* __restrict__ pos,
                               const int* __restrict__ offs, int* order) {
  int n = blockIdx.x * 256 + threadIdx.x;
  if (n < NT) order[offs[cid[n]] + pos[n]] = n;
}

// xs[i][:] = bf16(x[order[i]][:])  -- sorted, casted copy of x
__global__ void gather_cast(const float* __restrict__ x, const int* __restrict__ order,
                            bf16* __restrict__ xs) {
  int t = blockIdx.x * 256 + threadIdx.x;  // one thread per 8 elements
  int row = t >> 7;                        // 128 threads per row (1024 elems)
  if (row >= NT) return;
  int col = (t & 127) << 3;
  const f32x4* p = (const f32x4*)(x + (size_t)order[row] * DIM + col);
  f32x4 u = p[0], v = p[1];
  bf16x8 w;
  w[0] = (bf16)u[0]; w[1] = (bf16)u[1]; w[2] = (bf16)u[2]; w[3] = (bf16)u[3];
  w[4] = (bf16)v[0]; w[5] = (bf16)v[1]; w[6] = (bf16)v[2]; w[7] = (bf16)v[3];
  *(bf16x8*)(xs + (size_t)row * DIM + col) = w;
}

// dst[b][j][i] = bf16(src[b][i][j]) ; src is R x Cc per batch b
__global__ void transpose_cast(const float* __restrict__ src, bf16* __restrict__ dst,
                               int R, int Cc) {
  __shared__ float t[32][33];
  int b = blockIdx.z;
  int i0 = blockIdx.y * 32, j0 = blockIdx.x * 32;
  const float* s = src + (size_t)b * R * Cc;
  bf16* d = dst + (size_t)b * R * Cc;
  int tx = threadIdx.x & 31, ty = threadIdx.x >> 5;
#pragma unroll
  for (int yy = 0; yy < 32; yy += 8)
    t[ty + yy][tx] = s[(size_t)(i0 + ty + yy) * Cc + (j0 + tx)];
  __syncthreads();
#pragma unroll
  for (int yy = 0; yy < 32; yy += 8)
    d[(size_t)(j0 + ty + yy) * R + (i0 + tx)] = (bf16)t[tx][ty + yy];
}

// XCD-grouping decode: the 4 n-blocks of one (cluster,row-tile) group get
// dispatch slots congruent mod 8 -> same XCD L2 serves the shared A panel.
__device__ __forceinline__ bool decode_grp(int d, int& c, int& rt, int& j) {
  int x8 = d & 7, s = d >> 3;
  int g = (s >> 2) * 8 + x8;
  if (g >= NRT * NCLUS) return false;
  j = s & 3;
  c = g / NRT;
  rt = g - c * NRT;
  return true;
}

// ---------------- GEMM1: h1 = relu(xs @ W1[c]^T + b1[c]) ----------------

__global__ __launch_bounds__(256, 2) void gemm1_kernel(
    const bf16* __restrict__ xs, const bf16* __restrict__ w1t, const float* __restrict__ b1,
    const int* __restrict__ offs, const int* __restrict__ cnt, bf16* __restrict__ h1) {
  int c, rt, j;
  if (!decode_grp(blockIdx.x, c, rt, j)) return;
  int cntc = cnt[c];
  int row0 = rt * 128;
  if (row0 >= cntc) return;
  int seg = offs[c];
  int n0 = j * 128;

  __shared__ bf16 Als[128 * 64];  // [row][k]
  __shared__ bf16 Bls[128 * 64];  // [n][k]

  int tid = threadIdx.x;
  int lane = tid & 63, wid = tid >> 6;
  int wr = wid >> 1, wc = wid & 1;

  const bf16* aptr[4]; int aoff[4];
  const bf16* bptr[4]; int boff[4];
#pragma unroll
  for (int i = 0; i < 4; ++i) {
    int chunk = i * 4 + wid;              // 0..15, 512 bf16 per wave-chunk
    int r = chunk * 8 + (lane >> 3);      // tile row 0..127
    int kk = (lane & 7) << 3;
    int ar = seg + row0 + r; if (ar > NT - 1) ar = NT - 1;
    aptr[i] = xs + (size_t)ar * DIM + kk;
    aoff[i] = chunk * 512;
    bptr[i] = w1t + (size_t)(c * HID + n0 + r) * DIM + kk;
    boff[i] = chunk * 512;
  }

  f32x4 acc[4][4];
#pragma unroll
  for (int m = 0; m < 4; m++)
#pragma unroll
    for (int n = 0; n < 4; n++) acc[m][n] = {0.f, 0.f, 0.f, 0.f};

  for (int k0 = 0; k0 < DIM; k0 += 64) {
#pragma unroll
    for (int i = 0; i < 4; ++i) gload_lds16(aptr[i] + k0, &Als[aoff[i]]);
#pragma unroll
    for (int i = 0; i < 4; ++i) gload_lds16(bptr[i] + k0, &Bls[boff[i]]);
    __syncthreads();
#pragma unroll
    for (int ks = 0; ks < 2; ++ks) {
      int ko = ks * 32 + ((lane >> 4) << 3);
      bf16x8 a[4], b[4];
#pragma unroll
      for (int m = 0; m < 4; m++)
        a[m] = *(const bf16x8*)(&Als[(wr * 64 + m * 16 + (lane & 15)) * 64 + ko]);
#pragma unroll
      for (int n = 0; n < 4; n++)
        b[n] = *(const bf16x8*)(&Bls[(wc * 64 + n * 16 + (lane & 15)) * 64 + ko]);
#pragma unroll
      for (int m = 0; m < 4; m++)
#pragma unroll
        for (int n = 0; n < 4; n++)
          acc[m][n] = __builtin_amdgcn_mfma_f32_16x16x32_bf16(a[m], b[n], acc[m][n], 0, 0, 0);
    }
    __syncthreads();
  }

  int valid = cntc - row0; if (valid > 128) valid = 128;
#pragma unroll
  for (int n = 0; n < 4; n++) {
    int col = n0 + wc * 64 + n * 16 + (lane & 15);
    float bias = b1[c * HID + col];
#pragma unroll
    for (int m = 0; m < 4; m++) {
      int rbase = wr * 64 + m * 16 + ((lane >> 4) << 2);
#pragma unroll
      for (int e = 0; e < 4; e++) {
        int r = rbase + e;
        if (r < valid) {
          float v = acc[m][n][e] + bias;
          h1[(size_t)(seg + row0 + r) * HID + col] = (bf16)(v > 0.f ? v : 0.f);
        }
      }
    }
  }
}

// ---------------- GEMM2: pool[c] += colsum(relu(h1 @ W2[c]^T + b2[c])) ----------------

__global__ __launch_bounds__(256, 2) void gemm2_kernel(
    const bf16* __restrict__ h1, const bf16* __restrict__ w2t, const float* __restrict__ b2,
    const int* __restrict__ offs, const int* __restrict__ cnt, float* __restrict__ pool) {
  int c, rt, j;
  if (!decode_grp(blockIdx.x, c, rt, j)) return;
  int cntc = cnt[c];
  int row0 = rt * 128;
  if (row0 >= cntc) return;
  int seg = offs[c];
  int n0 = j * 128;
  int valid = cntc - row0; if (valid > 128) valid = 128;

  __shared__ bf16 Als[128 * 64];
  __shared__ bf16 Bls[128 * 64];

  int tid = threadIdx.x;
  int lane = tid & 63, wid = tid >> 6;
  int wr = wid >> 1, wc = wid & 1;

  const bf16* aptr[4]; int aoff[4];
  const bf16* bptr[4]; int boff[4];
#pragma unroll
  for (int i = 0; i < 4; ++i) {
    int chunk = i * 4 + wid;
    int r = chunk * 8 + (lane >> 3);
    int kk = (lane & 7) << 3;
    int ar = seg + row0 + r; if (ar > NT - 1) ar = NT - 1;
    aptr[i] = h1 + (size_t)ar * HID + kk;
    aoff[i] = chunk * 512;
    bptr[i] = w2t + (size_t)(c * HID + n0 + r) * HID + kk;
    boff[i] = chunk * 512;
  }

  f32x4 acc[4][4];
#pragma unroll
  for (int m = 0; m < 4; m++)
#pragma unroll
    for (int n = 0; n < 4; n++) acc[m][n] = {0.f, 0.f, 0.f, 0.f};

  for (int k0 = 0; k0 < HID; k0 += 64) {
#pragma unroll
    for (int i = 0; i < 4; ++i) gload_lds16(aptr[i] + k0, &Als[aoff[i]]);
#pragma unroll
    for (int i = 0; i < 4; ++i) gload_lds16(bptr[i] + k0, &Bls[boff[i]]);
    __syncthreads();
#pragma unroll
    for (int ks = 0; ks < 2; ++ks) {
      int ko = ks * 32 + ((lane >> 4) << 3);
      bf16x8 a[4], b[4];
#pragma unroll
      for (int m = 0; m < 4; m++)
        a[m] = *(const bf16x8*)(&Als[(wr * 64 + m * 16 + (lane & 15)) * 64 + ko]);
#pragma unroll
      for (int n = 0; n < 4; n++)
        b[n] = *(const bf16x8*)(&Bls[(wc * 64 + n * 16 + (lane & 15)) * 64 + ko]);
#pragma unroll
      for (int m = 0; m < 4; m++)
#pragma unroll
        for (int n = 0; n < 4; n++)
          acc[m][n] = __builtin_amdgcn_mfma_f32_16x16x32_bf16(a[m], b[n], acc[m][n], 0, 0, 0);
    }
    __syncthreads();
  }

  // bias + relu + masked column-sum into pool
#pragma unroll
  for (int n = 0; n < 4; n++) {
    int col = n0 + wc * 64 + n * 16 + (lane & 15);
    float bias = b2[c * HID + col];
    float s = 0.f;
#pragma unroll
    for (int m = 0; m < 4; m++) {
      int rbase = wr * 64 + m * 16 + ((lane >> 4) << 2);
#pragma unroll
      for (int e = 0; e < 4; e++) {
        if (rbase + e < valid) {
          float v = acc[m][n][e] + bias;
          s += (v > 0.f ? v : 0.f);
        }
      }
    }
    s += __shfl_xor(s, 16);
    s += __shfl_xor(s, 32);
    if (lane < 16) atomicAdd(&pool[c * HID + n0 + wc * 64 + n * 16 + lane], s);
  }
}

// ---------------- tails (fp32, parallelized) ----------------

// h[c][j] = relu(fcb[j] + sum_k (pool[c][k]/cnt) * fcW[k][j])
// grid: NCLUS*8 blocks (c, 64-wide j tile), 256 threads = 64 j x 4 k-groups
__global__ __launch_bounds__(256) void tail_fc(
    const float* __restrict__ pool, const int* __restrict__ cnt,
    const float* __restrict__ fcW, const float* __restrict__ fcb,
    float* __restrict__ hbuf) {
  int c = blockIdx.x >> 3;
  int jt = blockIdx.x & 7;
  __shared__ float hc[HID];
  __shared__ float red[4][64];
  int tid = threadIdx.x;
  float inv = 1.f / fmaxf((float)cnt[c], 1.f);
  for (int k = tid; k < HID; k += 256) hc[k] = pool[c * HID + k] * inv;
  __syncthreads();
  int jl = tid & 63, kg = tid >> 6;
  int j = jt * 64 + jl;
  float s = 0.f;
#pragma unroll 4
  for (int k = kg * 128; k < kg * 128 + 128; ++k) s += hc[k] * fcW[(size_t)k * HID + j];
  red[kg][jl] = s;
  __syncthreads();
  if (kg == 0) {
    float v = red[0][jl] + red[1][jl] + red[2][jl] + red[3][jl] + fcb[j];
    hbuf[c * HID + j] = fmaxf(v, 0.f);
  }
}

// score[c] = bc + sum_j tanh(h@Wa+ba)[j]*sigmoid(h@Wb+bb)[j]*Wc[j]
// grid: NCLUS blocks, 1024 threads = 256 j x 4 k-groups of 128
__global__ __launch_bounds__(1024) void tail_att(
    const float* __restrict__ hbuf,
    const float* __restrict__ Wa, const float* __restrict__ ba,
    const float* __restrict__ Wb, const float* __restrict__ bb,
    const float* __restrict__ Wc, const float* __restrict__ bc,
    float* __restrict__ score) {
  int c = blockIdx.x;
  __shared__ float h[HID];
  __shared__ float ra[4][DATT_N];
  __shared__ float rb[4][DATT_N];
  __shared__ float sc[DATT_N];
  int tid = threadIdx.x;
  for (int k = tid; k < HID; k += 1024) h[k] = hbuf[c * HID + k];
  __syncthreads();
  int jl = tid & 255, kg = tid >> 8;
  float sa = 0.f, sb = 0.f;
#pragma unroll 4
  for (int k = kg * 128; k < kg * 128 + 128; ++k) {
    float hv = h[k];
    sa += hv * Wa[(size_t)k * DATT_N + jl];
    sb += hv * Wb[(size_t)k * DATT_N + jl];
  }
  ra[kg][jl] = sa;
  rb[kg][jl] = sb;
  __syncthreads();
  if (kg == 0) {
    float va = ra[0][jl] + ra[1][jl] + ra[2][jl] + ra[3][jl] + ba[jl];
    float vb = rb[0][jl] + rb[1][jl] + rb[2][jl] + rb[3][jl] + bb[jl];
    float av = tanhf(va);
    float bv = 1.f / (1.f + expf(-vb));
    sc[jl] = av * bv * Wc[jl];
  }
  __syncthreads();
  for (int s2 = 128; s2 > 0; s2 >>= 1) {
    if (tid < s2) sc[tid] += sc[tid + s2];
    __syncthreads();
  }
  if (tid == 0) score[c] = sc[0] + bc[0];
}

// softmax over scores -> h_path -> rho -> classifier -> out
// 1 block, 1024 threads
__global__ __launch_bounds__(1024) void tail_fin(
    const float* __restrict__ score, const float* __restrict__ hbuf,
    const float* __restrict__ rhoW, const float* __restrict__ rhob,
    const float* __restrict__ clsW, const float* __restrict__ clsb,
    float* __restrict__ out) {
  __shared__ float Asm[NCLUS];
  __shared__ float hp[HID];
  __shared__ float rr[4][DATT_N];
  __shared__ float hr[DATT_N];
  __shared__ float lg[NCLS_N];
  int tid = threadIdx.x;
  if (tid == 0) {
    float mx = -1e30f;
    for (int c = 0; c < NCLUS; c++) mx = fmaxf(mx, score[c]);
    float sum = 0.f, e[NCLUS];
    for (int c = 0; c < NCLUS; c++) { e[c] = expf(score[c] - mx); sum += e[c]; }
    for (int c = 0; c < NCLUS; c++) Asm[c] = e[c] / sum;
  }
  __syncthreads();
  if (tid < HID) {
    float s = 0.f;
#pragma unroll
    for (int c = 0; c < NCLUS; c++) s += Asm[c] * hbuf[c * HID + tid];
    hp[tid] = s;
  }
  __syncthreads();
  int jl = tid & 255, kg = tid >> 8;
  float s = 0.f;
#pragma unroll 4
  for (int k = kg * 128; k < kg * 128 + 128; ++k) s += hp[k] * rhoW[(size_t)k * DATT_N + jl];
  rr[kg][jl] = s;
  __syncthreads();
  if (kg == 0) hr[jl] = fmaxf(rr[0][jl] + rr[1][jl] + rr[2][jl] + rr[3][jl] + rhob[jl], 0.f);
  __syncthreads();
  if (tid < NCLS_N * 64) {
    int t = tid >> 6, l = tid & 63;
    float cs = 0.f;
    for (int j = l; j < DATT_N; j += 64) cs += hr[j] * clsW[j * NCLS_N + t];
#pragma unroll
    for (int w = 32; w > 0; w >>= 1) cs += __shfl_xor(cs, w);
    if (l == 0) lg[t] = cs + clsb[t];
  }
  __syncthreads();
  if (tid == 0) {
    float mx = lg[0];
    int am = 0;
    for (int t = 1; t < NCLS_N; t++) if (lg[t] > mx) { mx = lg[t]; am = t; }
    float sum = 0.f, e[NCLS_N];
    for (int t = 0; t < NCLS_N; t++) { e[t] = expf(lg[t] - mx); sum += e[t]; }
    for (int t = 0; t < NCLS_N; t++) {
      out[t] = lg[t];
      out[NCLS_N + t] = e[t] / sum;
    }
    out[2 * NCLS_N] = (float)am;
  }
}

// ---------------- launch ----------------

extern "C" void kernel_launch(void* const* d_in, const int* in_sizes, int n_in,
                              void* d_out, int out_size, void* d_ws, size_t ws_size,
                              hipStream_t stream) {
  const float* x    = (const float*)d_in[0];
  const int*   cid  = (const int*)d_in[1];
  const float* W1   = (const float*)d_in[2];
  const float* b1   = (const float*)d_in[3];
  const float* W2   = (const float*)d_in[4];
  const float* b2   = (const float*)d_in[5];
  const float* fcW  = (const float*)d_in[6];
  const float* fcb  = (const float*)d_in[7];
  const float* Wa   = (const float*)d_in[8];
  const float* ba   = (const float*)d_in[9];
  const float* Wb   = (const float*)d_in[10];
  const float* bb   = (const float*)d_in[11];
  const float* Wc   = (const float*)d_in[12];
  const float* bc   = (const float*)d_in[13];
  const float* rhoW = (const float*)d_in[14];
  const float* rhob = (const float*)d_in[15];
  const float* clsW = (const float*)d_in[16];
  const float* clsb = (const float*)d_in[17];
  float* out = (float*)d_out;

  char* ws = (char*)d_ws;
  int*   cnt   = (int*)(ws + 0);
  int*   offs  = (int*)(ws + 64);
  float* score = (float*)(ws + 128);
  int*   pos   = (int*)(ws + 256);
  int*   order = (int*)(ws + 256 + 80000);
  float* pool  = (float*)(ws + 256 + 160000);
  float* hbuf  = (float*)(ws + 256 + 160000 + NCLUS * HID * 4);
  size_t o = 256 + 160000 + 2ull * NCLUS * HID * 4;
  o = (o + 255) & ~(size_t)255;
  bf16* w1t = (bf16*)(ws + o); o += (size_t)NCLUS * HID * DIM * 2;
  bf16* w2t = (bf16*)(ws + o); o += (size_t)NCLUS * HID * HID * 2;
  bf16* h1  = (bf16*)(ws + o); o += (size_t)NT * HID * 2;
  bf16* xs  = (bf16*)(ws + o); o += (size_t)NT * DIM * 2;

  zero_kernel<<<dim3((NCLUS * HID + 255) / 256), dim3(256), 0, stream>>>(cnt, pool);
  count_kernel<<<dim3((NT + 255) / 256), dim3(256), 0, stream>>>(cid, cnt, pos);
  offs_kernel<<<dim3(1), dim3(64), 0, stream>>>(cnt, offs);
  scatter_kernel<<<dim3((NT + 255) / 256), dim3(256), 0, stream>>>(cid, pos, offs, order);
  gather_cast<<<dim3(NT * 128 / 256), dim3(256), 0, stream>>>(x, order, xs);
  transpose_cast<<<dim3(HID / 32, DIM / 32, NCLUS), dim3(256), 0, stream>>>(W1, w1t, DIM, HID);
  transpose_cast<<<dim3(HID / 32, HID / 32, NCLUS), dim3(256), 0, stream>>>(W2, w2t, HID, HID);

  int nblk = 8 * ((NRT * NCLUS + 7) / 8) * 4;
  gemm1_kernel<<<dim3(nblk), dim3(256), 0, stream>>>(xs, w1t, b1, offs, cnt, h1);
  gemm2_kernel<<<dim3(nblk), dim3(256), 0, stream>>>(h1, w2t, b2, offs, cnt, pool);

  tail_fc<<<dim3(NCLUS * 8), dim3(256), 0, stream>>>(pool, cnt, fcW, fcb, hbuf);
  tail_att<<<dim3(NCLUS), dim3(1024), 0, stream>>>(hbuf, Wa, ba, Wb, bb, Wc, bc, score);
  tail_fin<<<dim3(1), dim3(1024), 0, stream>>>(score, hbuf, rhoW, rhob, clsW, clsb, out);
}

// Round 4
// 146.645 us; speedup vs baseline: 1.8095x; 1.4427x over previous
//
#include <hip/hip_runtime.h>
#include <hip/hip_bf16.h>
#include <stdint.h>

#define NT 20000
#define DIM 1024
#define HID 512
#define DATT_N 256
#define NCLUS 10
#define NCLS_N 4
#define NRT 157       // ceil(NT/128)
#define NBS 79        // ceil(NT/256) sort blocks

typedef __bf16 bf16;
typedef __attribute__((ext_vector_type(8))) __bf16 bf16x8;
typedef __attribute__((ext_vector_type(4))) float f32x4;

__device__ __forceinline__ void gload_lds16(const void* g, void* l) {
  __builtin_amdgcn_global_load_lds(
      (const __attribute__((address_space(1))) unsigned int*)g,
      (__attribute__((address_space(3))) unsigned int*)l, 16, 0, 0);
}

// ---------------- deterministic cluster sort (no global atomics) ----------------

__global__ void zero_pool(float* pool) {
  int i = blockIdx.x * 256 + threadIdx.x;
  if (i < NCLUS * HID) pool[i] = 0.f;
}

// per-block cluster histogram via wave ballots
__global__ __launch_bounds__(256) void hist_kernel(const int* __restrict__ cid,
                                                   int* __restrict__ blkcnt) {
  __shared__ int wcnt[4][16];
  int tid = threadIdx.x;
  int lane = tid & 63, w = tid >> 6;
  int n = blockIdx.x * 256 + tid;
  int mycid = (n < NT) ? cid[n] : -1;
#pragma unroll
  for (int c = 0; c < NCLUS; ++c) {
    unsigned long long m = __ballot(mycid == c);
    if (lane == c) wcnt[w][c] = __popcll(m);
  }
  __syncthreads();
  if (tid < NCLUS)
    blkcnt[blockIdx.x * NCLUS + tid] =
        wcnt[0][tid] + wcnt[1][tid] + wcnt[2][tid] + wcnt[3][tid];
}

// per-cluster scan over blocks -> blkbase, cnt, offs
__global__ void prefix_kernel(const int* __restrict__ blkcnt, int* __restrict__ blkbase,
                              int* __restrict__ cnt, int* __restrict__ offs) {
  int c = threadIdx.x;
  if (c < NCLUS) {
    int run = 0;
    for (int b = 0; b < NBS; ++b) {
      blkbase[b * NCLUS + c] = run;
      run += blkcnt[b * NCLUS + c];
    }
    cnt[c] = run;
  }
  __syncthreads();
  if (c == 0) {
    int a = 0;
    for (int i = 0; i < NCLUS; ++i) { offs[i] = a; a += cnt[i]; }
    offs[NCLUS] = a;
  }
}

// order[offs[c] + blkbase + waveprefix + rank_in_wave] = n
__global__ __launch_bounds__(256) void scatter2_kernel(
    const int* __restrict__ cid, const int* __restrict__ blkbase,
    const int* __restrict__ offs, int* __restrict__ order) {
  __shared__ int wcnt[4][16];
  __shared__ int wbase[4][16];
  int tid = threadIdx.x;
  int lane = tid & 63, w = tid >> 6;
  int n = blockIdx.x * 256 + tid;
  int mycid = (n < NT) ? cid[n] : -1;
  unsigned long long lmask = (lane == 63) ? ~0ull >> 1 : (1ull << lane) - 1;
  int myrank = 0;
#pragma unroll
  for (int c = 0; c < NCLUS; ++c) {
    unsigned long long m = __ballot(mycid == c);
    if (mycid == c) myrank = __popcll(m & lmask);
    if (lane == c) wcnt[w][c] = __popcll(m);
  }
  __syncthreads();
  if (tid < NCLUS) {
    int pre = blkbase[blockIdx.x * NCLUS + tid];
#pragma unroll
    for (int ww = 0; ww < 4; ++ww) { wbase[ww][tid] = pre; pre += wcnt[ww][tid]; }
  }
  __syncthreads();
  if (n < NT) order[offs[mycid] + wbase[w][mycid] + myrank] = n;
}

// xs[i][:] = bf16(x[order[i]][:])  -- sorted, casted copy of x
__global__ void gather_cast(const float* __restrict__ x, const int* __restrict__ order,
                            bf16* __restrict__ xs) {
  int t = blockIdx.x * 256 + threadIdx.x;  // one thread per 8 elements
  int row = t >> 7;                        // 128 threads per row (1024 elems)
  if (row >= NT) return;
  int col = (t & 127) << 3;
  const f32x4* p = (const f32x4*)(x + (size_t)order[row] * DIM + col);
  f32x4 u = p[0], v = p[1];
  bf16x8 w;
  w[0] = (bf16)u[0]; w[1] = (bf16)u[1]; w[2] = (bf16)u[2]; w[3] = (bf16)u[3];
  w[4] = (bf16)v[0]; w[5] = (bf16)v[1]; w[6] = (bf16)v[2]; w[7] = (bf16)v[3];
  *(bf16x8*)(xs + (size_t)row * DIM + col) = w;
}

// dst[b][j][i] = bf16(src[b][i][j]) ; src is R x Cc per batch b
__global__ void transpose_cast(const float* __restrict__ src, bf16* __restrict__ dst,
                               int R, int Cc) {
  __shared__ float t[32][33];
  int b = blockIdx.z;
  int i0 = blockIdx.y * 32, j0 = blockIdx.x * 32;
  const float* s = src + (size_t)b * R * Cc;
  bf16* d = dst + (size_t)b * R * Cc;
  int tx = threadIdx.x & 31, ty = threadIdx.x >> 5;
#pragma unroll
  for (int yy = 0; yy < 32; yy += 8)
    t[ty + yy][tx] = s[(size_t)(i0 + ty + yy) * Cc + (j0 + tx)];
  __syncthreads();
#pragma unroll
  for (int yy = 0; yy < 32; yy += 8)
    d[(size_t)(j0 + ty + yy) * R + (i0 + tx)] = (bf16)t[tx][ty + yy];
}

// XCD-grouping decode: the 4 n-blocks of one (cluster,row-tile) group get
// dispatch slots congruent mod 8 -> same XCD L2 serves the shared A panel.
__device__ __forceinline__ bool decode_grp(int d, int& c, int& rt, int& j) {
  int x8 = d & 7, s = d >> 3;
  int g = (s >> 2) * 8 + x8;
  if (g >= NRT * NCLUS) return false;
  j = s & 3;
  c = g / NRT;
  rt = g - c * NRT;
  return true;
}

// ---------------- GEMM1: h1 = relu(xs @ W1[c]^T + b1[c]) ----------------

__global__ __launch_bounds__(256, 2) void gemm1_kernel(
    const bf16* __restrict__ xs, const bf16* __restrict__ w1t, const float* __restrict__ b1,
    const int* __restrict__ offs, const int* __restrict__ cnt, bf16* __restrict__ h1) {
  int c, rt, j;
  if (!decode_grp(blockIdx.x, c, rt, j)) return;
  int cntc = cnt[c];
  int row0 = rt * 128;
  if (row0 >= cntc) return;
  int seg = offs[c];
  int n0 = j * 128;

  __shared__ bf16 Als[128 * 64];  // [row][k]
  __shared__ bf16 Bls[128 * 64];  // [n][k]

  int tid = threadIdx.x;
  int lane = tid & 63, wid = tid >> 6;
  int wr = wid >> 1, wc = wid & 1;

  const bf16* aptr[4]; int aoff[4];
  const bf16* bptr[4]; int boff[4];
#pragma unroll
  for (int i = 0; i < 4; ++i) {
    int chunk = i * 4 + wid;              // 0..15, 512 bf16 per wave-chunk
    int r = chunk * 8 + (lane >> 3);      // tile row 0..127
    int kk = (lane & 7) << 3;
    int ar = seg + row0 + r; if (ar > NT - 1) ar = NT - 1;
    aptr[i] = xs + (size_t)ar * DIM + kk;
    aoff[i] = chunk * 512;
    bptr[i] = w1t + (size_t)(c * HID + n0 + r) * DIM + kk;
    boff[i] = chunk * 512;
  }

  f32x4 acc[4][4];
#pragma unroll
  for (int m = 0; m < 4; m++)
#pragma unroll
    for (int n = 0; n < 4; n++) acc[m][n] = {0.f, 0.f, 0.f, 0.f};

  for (int k0 = 0; k0 < DIM; k0 += 64) {
#pragma unroll
    for (int i = 0; i < 4; ++i) gload_lds16(aptr[i] + k0, &Als[aoff[i]]);
#pragma unroll
    for (int i = 0; i < 4; ++i) gload_lds16(bptr[i] + k0, &Bls[boff[i]]);
    __syncthreads();
#pragma unroll
    for (int ks = 0; ks < 2; ++ks) {
      int ko = ks * 32 + ((lane >> 4) << 3);
      bf16x8 a[4], b[4];
#pragma unroll
      for (int m = 0; m < 4; m++)
        a[m] = *(const bf16x8*)(&Als[(wr * 64 + m * 16 + (lane & 15)) * 64 + ko]);
#pragma unroll
      for (int n = 0; n < 4; n++)
        b[n] = *(const bf16x8*)(&Bls[(wc * 64 + n * 16 + (lane & 15)) * 64 + ko]);
#pragma unroll
      for (int m = 0; m < 4; m++)
#pragma unroll
        for (int n = 0; n < 4; n++)
          acc[m][n] = __builtin_amdgcn_mfma_f32_16x16x32_bf16(a[m], b[n], acc[m][n], 0, 0, 0);
    }
    __syncthreads();
  }

  int valid = cntc - row0; if (valid > 128) valid = 128;
#pragma unroll
  for (int n = 0; n < 4; n++) {
    int col = n0 + wc * 64 + n * 16 + (lane & 15);
    float bias = b1[c * HID + col];
#pragma unroll
    for (int m = 0; m < 4; m++) {
      int rbase = wr * 64 + m * 16 + ((lane >> 4) << 2);
#pragma unroll
      for (int e = 0; e < 4; e++) {
        int r = rbase + e;
        if (r < valid) {
          float v = acc[m][n][e] + bias;
          h1[(size_t)(seg + row0 + r) * HID + col] = (bf16)(v > 0.f ? v : 0.f);
        }
      }
    }
  }
}

// ---------------- GEMM2: pool[c] += colsum(relu(h1 @ W2[c]^T + b2[c])) ----------------

__global__ __launch_bounds__(256, 2) void gemm2_kernel(
    const bf16* __restrict__ h1, const bf16* __restrict__ w2t, const float* __restrict__ b2,
    const int* __restrict__ offs, const int* __restrict__ cnt, float* __restrict__ pool) {
  int c, rt, j;
  if (!decode_grp(blockIdx.x, c, rt, j)) return;
  int cntc = cnt[c];
  int row0 = rt * 128;
  if (row0 >= cntc) return;
  int seg = offs[c];
  int n0 = j * 128;
  int valid = cntc - row0; if (valid > 128) valid = 128;

  __shared__ bf16 Als[128 * 64];
  __shared__ bf16 Bls[128 * 64];

  int tid = threadIdx.x;
  int lane = tid & 63, wid = tid >> 6;
  int wr = wid >> 1, wc = wid & 1;

  const bf16* aptr[4]; int aoff[4];
  const bf16* bptr[4]; int boff[4];
#pragma unroll
  for (int i = 0; i < 4; ++i) {
    int chunk = i * 4 + wid;
    int r = chunk * 8 + (lane >> 3);
    int kk = (lane & 7) << 3;
    int ar = seg + row0 + r; if (ar > NT - 1) ar = NT - 1;
    aptr[i] = h1 + (size_t)ar * HID + kk;
    aoff[i] = chunk * 512;
    bptr[i] = w2t + (size_t)(c * HID + n0 + r) * HID + kk;
    boff[i] = chunk * 512;
  }

  f32x4 acc[4][4];
#pragma unroll
  for (int m = 0; m < 4; m++)
#pragma unroll
    for (int n = 0; n < 4; n++) acc[m][n] = {0.f, 0.f, 0.f, 0.f};

  for (int k0 = 0; k0 < HID; k0 += 64) {
#pragma unroll
    for (int i = 0; i < 4; ++i) gload_lds16(aptr[i] + k0, &Als[aoff[i]]);
#pragma unroll
    for (int i = 0; i < 4; ++i) gload_lds16(bptr[i] + k0, &Bls[boff[i]]);
    __syncthreads();
#pragma unroll
    for (int ks = 0; ks < 2; ++ks) {
      int ko = ks * 32 + ((lane >> 4) << 3);
      bf16x8 a[4], b[4];
#pragma unroll
      for (int m = 0; m < 4; m++)
        a[m] = *(const bf16x8*)(&Als[(wr * 64 + m * 16 + (lane & 15)) * 64 + ko]);
#pragma unroll
      for (int n = 0; n < 4; n++)
        b[n] = *(const bf16x8*)(&Bls[(wc * 64 + n * 16 + (lane & 15)) * 64 + ko]);
#pragma unroll
      for (int m = 0; m < 4; m++)
#pragma unroll
        for (int n = 0; n < 4; n++)
          acc[m][n] = __builtin_amdgcn_mfma_f32_16x16x32_bf16(a[m], b[n], acc[m][n], 0, 0, 0);
    }
    __syncthreads();
  }

  // bias + relu + masked column-sum into pool
#pragma unroll
  for (int n = 0; n < 4; n++) {
    int col = n0 + wc * 64 + n * 16 + (lane & 15);
    float bias = b2[c * HID + col];
    float s = 0.f;
#pragma unroll
    for (int m = 0; m < 4; m++) {
      int rbase = wr * 64 + m * 16 + ((lane >> 4) << 2);
#pragma unroll
      for (int e = 0; e < 4; e++) {
        if (rbase + e < valid) {
          float v = acc[m][n][e] + bias;
          s += (v > 0.f ? v : 0.f);
        }
      }
    }
    s += __shfl_xor(s, 16);
    s += __shfl_xor(s, 32);
    if (lane < 16) atomicAdd(&pool[c * HID + n0 + wc * 64 + n * 16 + lane], s);
  }
}

// ---------------- tails (fp32, parallelized) ----------------

__global__ __launch_bounds__(256) void tail_fc(
    const float* __restrict__ pool, const int* __restrict__ cnt,
    const float* __restrict__ fcW, const float* __restrict__ fcb,
    float* __restrict__ hbuf) {
  int c = blockIdx.x >> 3;
  int jt = blockIdx.x & 7;
  __shared__ float hc[HID];
  __shared__ float red[4][64];
  int tid = threadIdx.x;
  float inv = 1.f / fmaxf((float)cnt[c], 1.f);
  for (int k = tid; k < HID; k += 256) hc[k] = pool[c * HID + k] * inv;
  __syncthreads();
  int jl = tid & 63, kg = tid >> 6;
  int j = jt * 64 + jl;
  float s = 0.f;
#pragma unroll 4
  for (int k = kg * 128; k < kg * 128 + 128; ++k) s += hc[k] * fcW[(size_t)k * HID + j];
  red[kg][jl] = s;
  __syncthreads();
  if (kg == 0) {
    float v = red[0][jl] + red[1][jl] + red[2][jl] + red[3][jl] + fcb[j];
    hbuf[c * HID + j] = fmaxf(v, 0.f);
  }
}

__global__ __launch_bounds__(1024) void tail_att(
    const float* __restrict__ hbuf,
    const float* __restrict__ Wa, const float* __restrict__ ba,
    const float* __restrict__ Wb, const float* __restrict__ bb,
    const float* __restrict__ Wc, const float* __restrict__ bc,
    float* __restrict__ score) {
  int c = blockIdx.x;
  __shared__ float h[HID];
  __shared__ float ra[4][DATT_N];
  __shared__ float rb[4][DATT_N];
  __shared__ float sc[DATT_N];
  int tid = threadIdx.x;
  for (int k = tid; k < HID; k += 1024) h[k] = hbuf[c * HID + k];
  __syncthreads();
  int jl = tid & 255, kg = tid >> 8;
  float sa = 0.f, sb = 0.f;
#pragma unroll 4
  for (int k = kg * 128; k < kg * 128 + 128; ++k) {
    float hv = h[k];
    sa += hv * Wa[(size_t)k * DATT_N + jl];
    sb += hv * Wb[(size_t)k * DATT_N + jl];
  }
  ra[kg][jl] = sa;
  rb[kg][jl] = sb;
  __syncthreads();
  if (kg == 0) {
    float va = ra[0][jl] + ra[1][jl] + ra[2][jl] + ra[3][jl] + ba[jl];
    float vb = rb[0][jl] + rb[1][jl] + rb[2][jl] + rb[3][jl] + bb[jl];
    float av = tanhf(va);
    float bv = 1.f / (1.f + expf(-vb));
    sc[jl] = av * bv * Wc[jl];
  }
  __syncthreads();
  for (int s2 = 128; s2 > 0; s2 >>= 1) {
    if (tid < s2) sc[tid] += sc[tid + s2];
    __syncthreads();
  }
  if (tid == 0) score[c] = sc[0] + bc[0];
}

__global__ __launch_bounds__(1024) void tail_fin(
    const float* __restrict__ score, const float* __restrict__ hbuf,
    const float* __restrict__ rhoW, const float* __restrict__ rhob,
    const float* __restrict__ clsW, const float* __restrict__ clsb,
    float* __restrict__ out) {
  __shared__ float Asm[NCLUS];
  __shared__ float hp[HID];
  __shared__ float rr[4][DATT_N];
  __shared__ float hr[DATT_N];
  __shared__ float lg[NCLS_N];
  int tid = threadIdx.x;
  if (tid == 0) {
    float mx = -1e30f;
    for (int c = 0; c < NCLUS; c++) mx = fmaxf(mx, score[c]);
    float sum = 0.f, e[NCLUS];
    for (int c = 0; c < NCLUS; c++) { e[c] = expf(score[c] - mx); sum += e[c]; }
    for (int c = 0; c < NCLUS; c++) Asm[c] = e[c] / sum;
  }
  __syncthreads();
  if (tid < HID) {
    float s = 0.f;
#pragma unroll
    for (int c = 0; c < NCLUS; c++) s += Asm[c] * hbuf[c * HID + tid];
    hp[tid] = s;
  }
  __syncthreads();
  int jl = tid & 255, kg = tid >> 8;
  float s = 0.f;
#pragma unroll 4
  for (int k = kg * 128; k < kg * 128 + 128; ++k) s += hp[k] * rhoW[(size_t)k * DATT_N + jl];
  rr[kg][jl] = s;
  __syncthreads();
  if (kg == 0) hr[jl] = fmaxf(rr[0][jl] + rr[1][jl] + rr[2][jl] + rr[3][jl] + rhob[jl], 0.f);
  __syncthreads();
  if (tid < NCLS_N * 64) {
    int t = tid >> 6, l = tid & 63;
    float cs = 0.f;
    for (int j = l; j < DATT_N; j += 64) cs += hr[j] * clsW[j * NCLS_N + t];
#pragma unroll
    for (int w = 32; w > 0; w >>= 1) cs += __shfl_xor(cs, w);
    if (l == 0) lg[t] = cs + clsb[t];
  }
  __syncthreads();
  if (tid == 0) {
    float mx = lg[0];
    int am = 0;
    for (int t = 1; t < NCLS_N; t++) if (lg[t] > mx) { mx = lg[t]; am = t; }
    float sum = 0.f, e[NCLS_N];
    for (int t = 0; t < NCLS_N; t++) { e[t] = expf(lg[t] - mx); sum += e[t]; }
    for (int t = 0; t < NCLS_N; t++) {
      out[t] = lg[t];
      out[NCLS_N + t] = e[t] / sum;
    }
    out[2 * NCLS_N] = (float)am;
  }
}

// ---------------- launch ----------------

extern "C" void kernel_launch(void* const* d_in, const int* in_sizes, int n_in,
                              void* d_out, int out_size, void* d_ws, size_t ws_size,
                              hipStream_t stream) {
  const float* x    = (const float*)d_in[0];
  const int*   cid  = (const int*)d_in[1];
  const float* W1   = (const float*)d_in[2];
  const float* b1   = (const float*)d_in[3];
  const float* W2   = (const float*)d_in[4];
  const float* b2   = (const float*)d_in[5];
  const float* fcW  = (const float*)d_in[6];
  const float* fcb  = (const float*)d_in[7];
  const float* Wa   = (const float*)d_in[8];
  const float* ba   = (const float*)d_in[9];
  const float* Wb   = (const float*)d_in[10];
  const float* bb   = (const float*)d_in[11];
  const float* Wc   = (const float*)d_in[12];
  const float* bc   = (const float*)d_in[13];
  const float* rhoW = (const float*)d_in[14];
  const float* rhob = (const float*)d_in[15];
  const float* clsW = (const float*)d_in[16];
  const float* clsb = (const float*)d_in[17];
  float* out = (float*)d_out;

  char* ws = (char*)d_ws;
  int*   cnt     = (int*)(ws + 0);
  int*   offs    = (int*)(ws + 64);
  float* score   = (float*)(ws + 128);
  int*   blkcnt  = (int*)(ws + 256);                    // NBS*NCLUS = 790 ints
  int*   blkbase = (int*)(ws + 256 + 4096);
  int*   order   = (int*)(ws + 256 + 8192);             // NT ints
  float* pool    = (float*)(ws + 256 + 8192 + 80000);
  float* hbuf    = (float*)(ws + 256 + 8192 + 80000 + NCLUS * HID * 4);
  size_t o = 256 + 8192 + 80000 + 2ull * NCLUS * HID * 4;
  o = (o + 255) & ~(size_t)255;
  bf16* w1t = (bf16*)(ws + o); o += (size_t)NCLUS * HID * DIM * 2;
  bf16* w2t = (bf16*)(ws + o); o += (size_t)NCLUS * HID * HID * 2;
  bf16* h1  = (bf16*)(ws + o); o += (size_t)NT * HID * 2;
  bf16* xs  = (bf16*)(ws + o); o += (size_t)NT * DIM * 2;

  zero_pool<<<dim3((NCLUS * HID + 255) / 256), dim3(256), 0, stream>>>(pool);
  hist_kernel<<<dim3(NBS), dim3(256), 0, stream>>>(cid, blkcnt);
  prefix_kernel<<<dim3(1), dim3(64), 0, stream>>>(blkcnt, blkbase, cnt, offs);
  scatter2_kernel<<<dim3(NBS), dim3(256), 0, stream>>>(cid, blkbase, offs, order);
  gather_cast<<<dim3(NT * 128 / 256), dim3(256), 0, stream>>>(x, order, xs);
  transpose_cast<<<dim3(HID / 32, DIM / 32, NCLUS), dim3(256), 0, stream>>>(W1, w1t, DIM, HID);
  transpose_cast<<<dim3(HID / 32, HID / 32, NCLUS), dim3(256), 0, stream>>>(W2, w2t, HID, HID);

  int nblk = 8 * ((NRT * NCLUS + 7) / 8) * 4;
  gemm1_kernel<<<dim3(nblk), dim3(256), 0, stream>>>(xs, w1t, b1, offs, cnt, h1);
  gemm2_kernel<<<dim3(nblk), dim3(256), 0, stream>>>(h1, w2t, b2, offs, cnt, pool);

  tail_fc<<<dim3(NCLUS * 8), dim3(256), 0, stream>>>(pool, cnt, fcW, fcb, hbuf);
  tail_att<<<dim3(NCLUS), dim3(1024), 0, stream>>>(hbuf, Wa, ba, Wb, bb, Wc, bc, score);
  tail_fin<<<dim3(1), dim3(1024), 0, stream>>>(score, hbuf, rhoW, rhob, clsW, clsb, out);
}